// Round 2
// baseline (505.916 us; speedup 1.0000x reference)
//
#include <hip/hip_runtime.h>

// upfirdn2d depthwise 4x4 blur, kernel = outer([1,3,3,1],[1,3,3,1])/64.
// x: (16,256,128,128) f32 -> out: (16,256,127,127) f32, zero pad (1,1)/(1,1).
//
// v4: streaming-store + MLP pass over v3.
//  - Output is write-once, never re-read: use __builtin_nontemporal_store
//    (nt flag) so the 264 MB write stream does not allocate in L2, leaving
//    L2 for the input halo re-reads (+9% inter-split overlap) and the
//    concurrent read stream.
//  - #pragma unroll 8 (was 4): doubles independent global loads in flight
//    per wave. VGPR cost ~16, far from any occupancy cliff.
//  - Store path unchanged from v3: ONE global_store_dwordx4 per lane per
//    row; lane 31 stores {col123..126} at po-1 (col 123 double-written with
//    the identical value).
// Layout: one block (128 thr) per image; lane c = tid&31 owns cols 4c..4c+3,
// split s = tid>>5 owns output rows 32s..32s+31. 4096 blocks x 2 waves
// = 32 waves/CU (full occupancy).

#define IW 128
#define IH 128
#define OW 127
#define OH 127

typedef float f4u __attribute__((ext_vector_type(4), aligned(4)));

__global__ __launch_bounds__(128)
void upfirdn2d_blur_v4(const float4* __restrict__ x, float* __restrict__ out) {
    const int tid = threadIdx.x;
    const int c   = tid & 31;        // column group: input cols 4c..4c+3
    const int s   = tid >> 5;        // row split: output rows 32s..32s+31
    const int img = blockIdx.x;      // n*C + c  (4096 images)

    const float4* __restrict__ in4 = x + (size_t)img * (IH * IW / 4);
    float*        __restrict__ o   = out + (size_t)img * (OH * OW);

    const float mL   = (c > 0)  ? 1.0f : 0.0f;   // col 4c-1 valid?
    const float mR   = (c < 31) ? 1.0f : 0.0f;   // cols 4c+4, 4c+5 valid?
    const bool  edge = (c == 31);
    const int lm1 = (tid - 1) & 63;              // lane within wave
    const int lp1 = (tid + 1) & 63;

    // per-thread store base: lane 31 shifts left by one col (overlap trick)
    float* const obase = o + 4 * c - (edge ? 1 : 0);

    // horizontal 4-tap (1,3,3,1 unnormalized) on 4 columns from one float4
    auto hrow = [&](int r) -> float4 {
        const float4 v = in4[r * (IW / 4) + c];
        const float l  = mL * __shfl(v.w, lm1, 64);   // col 4c-1
        const float r0 = mR * __shfl(v.x, lp1, 64);   // col 4c+4
        const float r1 = mR * __shfl(v.y, lp1, 64);   // col 4c+5
        float4 h;
        h.x = l   + 3.0f * (v.x + v.y) + v.z;
        h.y = v.x + 3.0f * (v.y + v.z) + v.w;
        h.z = v.y + 3.0f * (v.z + v.w) + r0;
        h.w = v.z + 3.0f * (v.w + r0)  + r1;
        return h;
    };

    const int y0 = 32 * s;

    // rolling vertical window: out[y] = (h[y-1] + 3h[y] + 3h[y+1] + h[y+2])/64
    float4 hm1 = hrow(y0 > 0 ? y0 - 1 : 0);
    const float mTop = (y0 > 0) ? 1.0f : 0.0f;       // h(-1) = 0 (top pad)
    hm1.x *= mTop; hm1.y *= mTop; hm1.z *= mTop; hm1.w *= mTop;
    float4 h0 = hrow(y0);
    float4 h1 = hrow(y0 + 1);

    #pragma unroll 8
    for (int i = 0; i < 32; ++i) {
        const int y  = y0 + i;
        const int r2 = y + 2;
        const float m2 = (r2 < IH) ? 1.0f : 0.0f;    // h(128) = 0 (bottom pad)
        float4 h2 = hrow(r2 < IH ? r2 : IH - 1);
        h2.x *= m2; h2.y *= m2; h2.z *= m2; h2.w *= m2;

        if (y < OH) {                                 // s==3 skips y==127
            float4 t;
            t.x = (hm1.x + 3.0f * (h0.x + h1.x) + h2.x) * 0.015625f;
            t.y = (hm1.y + 3.0f * (h0.y + h1.y) + h2.y) * 0.015625f;
            t.z = (hm1.z + 3.0f * (h0.z + h1.z) + h2.z) * 0.015625f;
            t.w = (hm1.w + 3.0f * (h0.w + h1.w) + h2.w) * 0.015625f;

            // lane 31 pulls lane 30's t.w (= output col 123); its own t.w
            // (col 127) doesn't exist and is dropped.
            const float tw = __shfl(t.w, lm1, 64);
            f4u sv;
            sv[0] = edge ? tw  : t.x;
            sv[1] = edge ? t.x : t.y;
            sv[2] = edge ? t.y : t.z;
            sv[3] = edge ? t.z : t.w;
            // nt store: bypass L2 allocation for the write-once output
            __builtin_nontemporal_store(sv, (f4u*)(obase + y * OW));
        }
        hm1 = h0; h0 = h1; h1 = h2;
    }
}

extern "C" void kernel_launch(void* const* d_in, const int* in_sizes, int n_in,
                              void* d_out, int out_size, void* d_ws, size_t ws_size,
                              hipStream_t stream) {
    const float4* x = (const float4*)d_in[0];
    float* out = (float*)d_out;
    const int n_imgs = 16 * 256;     // N*C
    hipLaunchKernelGGL(upfirdn2d_blur_v4, dim3(n_imgs), dim3(128), 0, stream,
                       x, out);
}

// Round 3
// 437.417 us; speedup vs baseline: 1.1566x; 1.1566x over previous
//
#include <hip/hip_runtime.h>

// upfirdn2d depthwise 4x4 blur, kernel = outer([1,3,3,1],[1,3,3,1])/64.
// x: (16,256,128,128) f32 -> out: (16,256,127,127) f32, zero pad (1,1)/(1,1).
//
// v5: two-phase load-burst structure (revert v4's nt store — it caused
// partial-line HBM writes, kernel 171 -> 212 us).
//  Diagnosis from v4 counters: kernel is latency-bound (2 TB/s, VALUBusy 7.7%,
//  traffic near-ideal). Suspected limiter: per-iteration load->compute->store
//  interleave puts stores between loads in the shared vmcnt queue, so each
//  load wait also drains prior stores; per-wave MLP stays shallow.
//  Fix: 8 row-bands of 16 per image (256-thr block). Each thread bursts all
//  19 row loads (y0-1 .. y0+17) into registers FIRST (pure descending-vmcnt
//  consumption, no store ever ahead of a dependent load), then computes the
//  16 output rows with the rolling 4-tap window and stores.
//  Cost: ~76 VGPR prefetch state (-> ~4 waves/SIMD resident, ample MLP),
//  +18.75% band-halo reads that hit L2 (same block, adjacent bands).
// Store path (from v3): ONE global_store_dwordx4 per lane per row; lane 31
// stores {col123..126} at obase-1 (col 123 double-written, same value).

#define IW 128
#define IH 128
#define OW 127
#define OH 127
#define NPF 19   // prefetched input rows per thread: y0-1 .. y0+17

typedef float f4u __attribute__((ext_vector_type(4), aligned(4)));

__global__ __launch_bounds__(256)
void upfirdn2d_blur_v5(const float4* __restrict__ x, float* __restrict__ out) {
    const int tid  = threadIdx.x;
    const int lane = tid & 63;
    const int c    = lane & 31;      // column group: input cols 4c..4c+3
    const int s    = tid >> 5;       // row band: output rows 16s..16s+15
    const int img  = blockIdx.x;     // n*C + c  (4096 images)

    const float4* __restrict__ in4 = x + (size_t)img * (IH * IW / 4);
    float*        __restrict__ o   = out + (size_t)img * (OH * OW);

    const float mL   = (c > 0)  ? 1.0f : 0.0f;   // col 4c-1 valid?
    const float mR   = (c < 31) ? 1.0f : 0.0f;   // cols 4c+4, 4c+5 valid?
    const bool  edge = (c == 31);
    const int lm1 = (lane - 1) & 63;
    const int lp1 = (lane + 1) & 63;

    // per-thread store base: lane 31 shifts left by one col (overlap trick)
    float* const obase = o + 4 * c - (edge ? 1 : 0);

    const int y0 = 16 * s;

    // ---- phase 1: burst all 19 row loads (independent, no stores issued) ----
    float4 pf[NPF];
    #pragma unroll
    for (int j = 0; j < NPF; ++j) {
        int r = y0 - 1 + j;                       // -1..129 across bands
        r = r < 0 ? 0 : (r > IH - 1 ? IH - 1 : r);
        pf[j] = in4[r * (IW / 4) + c];
    }

    // horizontal 4-tap (1,3,3,1 unnormalized), zero-masked for pad rows
    auto hof = [&](const float4 v, const float m) -> float4 {
        const float l  = mL * __shfl(v.w, lm1, 64);   // col 4c-1
        const float r0 = mR * __shfl(v.x, lp1, 64);   // col 4c+4
        const float r1 = mR * __shfl(v.y, lp1, 64);   // col 4c+5
        float4 h;
        h.x = (l   + 3.0f * (v.x + v.y) + v.z) * m;
        h.y = (v.x + 3.0f * (v.y + v.z) + v.w) * m;
        h.z = (v.y + 3.0f * (v.z + v.w) + r0)  * m;
        h.w = (v.z + 3.0f * (v.w + r0)  + r1)  * m;
        return h;
    };

    // ---- phase 2: rolling vertical window over prefetched rows ----
    // h[j] corresponds to input row y0-1+j; pad rows (r<0 or r>=IH) -> 0.
    float4 hm1 = hof(pf[0], (s == 0) ? 0.0f : 1.0f);  // row y0-1
    float4 h0  = hof(pf[1], 1.0f);                    // row y0
    float4 h1  = hof(pf[2], 1.0f);                    // row y0+1

    #pragma unroll
    for (int i = 0; i < 16; ++i) {
        const int j2 = i + 3;                         // row y0+i+2
        const float m2 = (y0 + i + 2 < IH) ? 1.0f : 0.0f;
        float4 h2 = hof(pf[j2], m2);

        const int y = y0 + i;
        if (y < OH) {                                 // s==7 skips y==127
            float4 t;
            t.x = (hm1.x + 3.0f * (h0.x + h1.x) + h2.x) * 0.015625f;
            t.y = (hm1.y + 3.0f * (h0.y + h1.y) + h2.y) * 0.015625f;
            t.z = (hm1.z + 3.0f * (h0.z + h1.z) + h2.z) * 0.015625f;
            t.w = (hm1.w + 3.0f * (h0.w + h1.w) + h2.w) * 0.015625f;

            // lane 31 pulls lane 30's t.w (= output col 123); its own t.w
            // (col 127) doesn't exist and is dropped.
            const float tw = __shfl(t.w, lm1, 64);
            f4u sv;
            sv[0] = edge ? tw  : t.x;
            sv[1] = edge ? t.x : t.y;
            sv[2] = edge ? t.y : t.z;
            sv[3] = edge ? t.z : t.w;
            *(f4u*)(obase + y * OW) = sv;             // ONE dwordx4 per row
        }
        hm1 = h0; h0 = h1; h1 = h2;
    }
}

extern "C" void kernel_launch(void* const* d_in, const int* in_sizes, int n_in,
                              void* d_out, int out_size, void* d_ws, size_t ws_size,
                              hipStream_t stream) {
    const float4* x = (const float4*)d_in[0];
    float* out = (float*)d_out;
    const int n_imgs = 16 * 256;     // N*C
    hipLaunchKernelGGL(upfirdn2d_blur_v5, dim3(n_imgs), dim3(256), 0, stream,
                       x, out);
}